// Round 9
// baseline (2749.839 us; speedup 1.0000x reference)
//
#include <hip/hip_runtime.h>

// PointNet++ SetAbstraction: FPS -> ball query -> grouped MLP(67->64->64->128, BN+ReLU) -> maxpool
// B=8, N=8192, S=2048, K=32, F=64.
//
// d_out: [8][2048][3] center_xyzs then [8][2048][128] center_feats (fp32).
// d_ws: 16576 floats of transposed weights.
//
// EXACTNESS INVARIANTS (validated R4..R8: absmax 7.8e-3 < 5.4e-2):
//   - discrete-decision math in contract(off) helpers; __f*_rn does NOT block FMA.
//   - np.sum last-axis n=3: FORWARD plain adds (x0+x1)+x2  [FPS dist, |c|^2, |x|^2]
//   - einsum dot: ascending FMA chain fma(c2,x2, fma(c1,x1, c0*x0))  [ball query]
//   - FPS argmax: u64 key (float_bits(bv)<<13)|(8191-idx); bv in [0,3] so float
//     bits are monotone; pure max(key) == (max bv, tie -> min idx). Total order.
//   - packed v2f math: v_pk_add/mul_f32 round identically to scalar per half.
//
// PERF LESSONS:
//   R5: dynamically-indexed per-thread arrays get LDS-demoted — named vectors only.
//   R6/R7: __shfl_* lowers to ds_permute (LDS pipe) — use DPP for reductions.
//   R8: DPP reduce 3504->1998 us; now ~85% VALUBusy on the 8 active CUs with
//       ~1300 cyc/step of unhidden latency at 2 waves/SIMD.
//   R9: 1024 thr (4 waves/SIMD latency hiding) + packed-f32 distance math
//       (halves dist-loop issue) + 16-slot row_ror cross-wave scan.
//   sa_fused_kernel byte-identical to R4.

#define NPTS 8192
#define SCTR 2048
#define NB   8
#define KNN  32
#define NF   64

typedef float v2f __attribute__((ext_vector_type(2)));

// d = (dx*dx + dy*dy) + dz*dz for TWO points, exact fp32 mul/add order,
// NO contraction (maps to v_pk_add_f32 / v_pk_mul_f32 — same IEEE rounding).
__device__ __forceinline__ v2f fps_sqdist_v2(v2f px, v2f py, v2f pz,
                                             v2f lx, v2f ly, v2f lz) {
#pragma clang fp contract(off)
  v2f dx = px - lx;
  v2f dy = py - ly;
  v2f dz = pz - lz;
  v2f xx = dx * dx;
  v2f yy = dy * dy;
  v2f zz = dz * dz;
  return (xx + yy) + zz;
}

// (x*x + y*y) + z*z, NO contraction (np.sum forward order, n=3).
__device__ __forceinline__ float sumsq3(float x, float y, float z) {
#pragma clang fp contract(off)
  return (x * x + y * y) + z * z;
}

// Ball-query expanded form: (sc + sx) - 2*dot, NO contraction on the adds.
// dot = ascending-k FMA chain: fma(cz,z, fma(cy,y, cx*x)).
__device__ __forceinline__ float bq_d2(float sc, float sx,
                                       float cx, float cy, float cz,
                                       float x, float y, float z) {
#pragma clang fp contract(off)
  float dt = fmaf(cz, z, fmaf(cy, y, cx * x));
  return (sc + sx) - 2.0f * dt;
}

// u64 max with the partner lane's key fetched via DPP (VALU pipe, no LDS).
// old=src (self): bound-disabled lanes combine with themselves (idempotent max).
template <int CTRL>
__device__ __forceinline__ unsigned long long kmax_dpp(unsigned long long k) {
  int lo = (int)(unsigned int)(k & 0xFFFFFFFFull);
  int hi = (int)(unsigned int)(k >> 32);
  int slo = __builtin_amdgcn_update_dpp(lo, lo, CTRL, 0xF, 0xF, false);
  int shi = __builtin_amdgcn_update_dpp(hi, hi, CTRL, 0xF, 0xF, false);
  unsigned long long sk =
      ((unsigned long long)(unsigned int)shi << 32) | (unsigned int)slo;
  return sk > k ? sk : k;
}

// ---------------------------------------------------------------------------
// Kernel 1: blocks 0..7 = FPS (one block per batch, 1024 thr = 16 waves,
// 8 points/thread in NAMED float4 registers, packed-f32 distance math);
// blocks 8..24 = weight transpose. Argmax reduction on the VALU pipe via DPP;
// LDS only for 16 wave-best slots, winner-coord broadcast, and writeback.
// ---------------------------------------------------------------------------
__global__ __launch_bounds__(1024, 4) void fps_transpose_kernel(
    const float* __restrict__ xyzs,
    const float* __restrict__ w1, const float* __restrict__ w2, const float* __restrict__ w3,
    float* __restrict__ centers, float* __restrict__ wT)
{
  const int t = threadIdx.x;
  if (blockIdx.x >= NB) {
    int idx = (blockIdx.x - NB) * 1024 + t;
    if (idx < 67*64) {
      int c = idx >> 6, o = idx & 63;
      wT[idx] = w1[o*67 + c];
    } else if (idx < 67*64 + 64*64) {
      int r = idx - 67*64; int c = r >> 6, o = r & 63;
      wT[idx] = w2[o*64 + c];
    } else if (idx < 67*64 + 64*64 + 64*128) {
      int r = idx - (67*64 + 64*64); int c = r >> 7, o = r & 127;
      wT[idx] = w3[o*64 + c];
    }
    return;
  }

  const int b = blockIdx.x;
  const float* xb = xyzs + (size_t)b * NPTS * 3;

  __shared__ float sX[NPTS], sY[NPTS], sZ[NPTS];         // 96 KB planar coords
  __shared__ unsigned long long redk[2][16];             // wave-best keys
  __shared__ int hist[SCTR];                             // 8 KB

  // One-time fill of the planar LDS copies (off the hot path).
  for (int i = t; i < NPTS; i += 1024) {
    sX[i] = xb[3*i+0];
    sY[i] = xb[3*i+1];
    sZ[i] = xb[3*i+2];
  }
  if (t == 0) hist[0] = 0;   // reference: first center is index 0
  __syncthreads();

  const int t4 = 4 * t;

  // 8 loop-invariant points (2 quads strided 4096) in NAMED registers.
  const float4 xA = *(const float4*)(sX + 0    + t4);
  const float4 yA = *(const float4*)(sY + 0    + t4);
  const float4 zA = *(const float4*)(sZ + 0    + t4);
  const float4 xB = *(const float4*)(sX + 4096 + t4);
  const float4 yB = *(const float4*)(sY + 4096 + t4);
  const float4 zB = *(const float4*)(sZ + 4096 + t4);

  float4 mA = make_float4(1e10f,1e10f,1e10f,1e10f);
  float4 mB = mA;

  float lx = sX[0], ly = sY[0], lz = sZ[0];

  for (int s = 1; s < SCTR; ++s) {
    float bv = -1.0f; int bg = 0;
    {
      v2f lxv = {lx, lx}, lyv = {ly, ly}, lzv = {lz, lz};

      // Quad A (pts t4+0..3), packed two-at-a-time.
      v2f d;
      d = fps_sqdist_v2((v2f){xA.x,xA.y}, (v2f){yA.x,yA.y}, (v2f){zA.x,zA.y},
                        lxv, lyv, lzv);
      mA.x = fminf(mA.x, d.x); if (mA.x > bv) { bv = mA.x; bg = t4 + 0; }
      mA.y = fminf(mA.y, d.y); if (mA.y > bv) { bv = mA.y; bg = t4 + 1; }
      d = fps_sqdist_v2((v2f){xA.z,xA.w}, (v2f){yA.z,yA.w}, (v2f){zA.z,zA.w},
                        lxv, lyv, lzv);
      mA.z = fminf(mA.z, d.x); if (mA.z > bv) { bv = mA.z; bg = t4 + 2; }
      mA.w = fminf(mA.w, d.y); if (mA.w > bv) { bv = mA.w; bg = t4 + 3; }

      // Quad B (pts 4096+t4+0..3).
      d = fps_sqdist_v2((v2f){xB.x,xB.y}, (v2f){yB.x,yB.y}, (v2f){zB.x,zB.y},
                        lxv, lyv, lzv);
      mB.x = fminf(mB.x, d.x); if (mB.x > bv) { bv = mB.x; bg = 4096 + t4 + 0; }
      mB.y = fminf(mB.y, d.y); if (mB.y > bv) { bv = mB.y; bg = 4096 + t4 + 1; }
      d = fps_sqdist_v2((v2f){xB.z,xB.w}, (v2f){yB.z,yB.w}, (v2f){zB.z,zB.w},
                        lxv, lyv, lzv);
      mB.z = fminf(mB.z, d.x); if (mB.z > bv) { bv = mB.z; bg = 4096 + t4 + 2; }
      mB.w = fminf(mB.w, d.y); if (mB.w > bv) { bv = mB.w; bg = 4096 + t4 + 3; }
    }

    // Pack: bv >= 0, so float bits are order-monotone.
    unsigned long long key =
        ((unsigned long long)__float_as_uint(bv) << 13) |
        (unsigned long long)(8191 - bg);

    // Wave-level max on the VALU pipe; lane 63 holds the wave max after this.
    key = kmax_dpp<0x111>(key);   // row_shr:1
    key = kmax_dpp<0x112>(key);   // row_shr:2
    key = kmax_dpp<0x114>(key);   // row_shr:4
    key = kmax_dpp<0x118>(key);   // row_shr:8
    key = kmax_dpp<0x142>(key);   // row_bcast:15
    key = kmax_dpp<0x143>(key);   // row_bcast:31

    int pb = s & 1;   // double-buffered slots: one barrier per step
    if ((t & 63) == 63) redk[pb][t >> 6] = key;
    __syncthreads();

    // Cross-wave: lane reads slot (lane&15), then circular max-reduce over the
    // 16 replicated slots via row_ror 1,2,4,8 (window doubles each hop).
    unsigned long long k16 = redk[pb][t & 15];
    k16 = kmax_dpp<0x121>(k16);   // row_ror:1
    k16 = kmax_dpp<0x122>(k16);   // row_ror:2
    k16 = kmax_dpp<0x124>(k16);   // row_ror:4
    k16 = kmax_dpp<0x128>(k16);   // row_ror:8

    int i0 = 8191 - (int)(k16 & 0x1FFFull);
    // Winner coords: broadcast LDS reads (same address all lanes — free).
    lx = sX[i0]; ly = sY[i0]; lz = sZ[i0];
    if (t == 0) hist[s] = i0;
  }
  __syncthreads();

  for (int s = t; s < SCTR; s += 1024) {
    int i = hist[s];
    float* o = centers + ((size_t)b * SCTR + s) * 3;
    o[0] = sX[i]; o[1] = sY[i]; o[2] = sZ[i];
  }
}

// ---------------------------------------------------------------------------
// Kernel 2: one 64-thread wave per center. Ball query (first K ascending
// index within radius, exact expanded-form d2), gather to LDS, 3-layer MLP
// with per-lane 4k x 8o register tile, BN+ReLU, maxpool over K, store.
// (byte-identical to the R4 passing version)
// ---------------------------------------------------------------------------
__global__ __launch_bounds__(64) void sa_fused_kernel(
    const float* __restrict__ xyzs, const float* __restrict__ feats,
    const float* centers, const float* __restrict__ wT,
    const float* __restrict__ b1, const float* __restrict__ g1, const float* __restrict__ bt1,
    const float* __restrict__ m1, const float* __restrict__ v1,
    const float* __restrict__ b2, const float* __restrict__ g2, const float* __restrict__ bt2,
    const float* __restrict__ m2, const float* __restrict__ v2,
    const float* __restrict__ b3, const float* __restrict__ g3, const float* __restrict__ bt3,
    const float* __restrict__ m3, const float* __restrict__ v3,
    float* out_feats)
{
  constexpr float R2 = (float)(0.2 * 0.2);  // f32(0.04000000000000001) — matches ref predicate
  const int bid  = blockIdx.x;
  const int b    = bid >> 11;
  const int lane = threadIdx.x;
  const float* xb = xyzs + (size_t)b * NPTS * 3;
  const float* cp = centers + (size_t)bid * 3;
  float cx = cp[0], cy = cp[1], cz = cp[2];
  float sc = sumsq3(cx, cy, cz);

  __shared__ int   gidx[KNN];
  __shared__ float in_[32*67];   // stride 67 (conflict-free for the 4k in-reads)
  __shared__ float y_[32*65];    // stride 65

  // ---- ball query: first 32 in-radius points by ascending index ----
  int cnt = 0;
  for (int base = 0; base < NPTS && cnt < KNN; base += 64) {
    int n = base + lane;
    float x = xb[n*3+0], y = xb[n*3+1], z = xb[n*3+2];
    float sx = sumsq3(x, y, z);
    float d2 = bq_d2(sc, sx, cx, cy, cz, x, y, z);
    bool within = (d2 <= R2);
    unsigned long long mk = __ballot(within);
    int rank = __popcll(mk & ((1ull << lane) - 1ull));
    int slot = cnt + rank;
    if (within && slot < KNN) gidx[slot] = n;
    cnt += (int)__popcll(mk);
  }
  if (cnt > KNN) cnt = KNN;
  __syncthreads();

  // ---- gather: in_[k][0..2] = xyz - center, in_[k][3..66] = feats; zeros if invalid ----
#pragma unroll 4
  for (int k = 0; k < KNN; ++k) {
    int gk = (k < cnt) ? gidx[k] : -1;
    float fv = 0.f, xv = 0.f;
    if (gk >= 0) {
      fv = feats[((size_t)b * NPTS + gk) * NF + lane];
      if (lane < 3) xv = xb[gk*3 + lane] - cp[lane];  // exact single op
    }
    in_[k*67 + 3 + lane] = fv;
    if (lane < 3) in_[k*67 + lane] = xv;
  }
  __syncthreads();

  const int g = lane >> 3;  // k-group: k = 4g..4g+3
  const int h = lane & 7;   // o-group: o = 8h..8h+7
  const float* w1T = wT;                  // [67][64]
  const float* w2T = wT + 67*64;          // [64][64]
  const float* w3T = wT + 67*64 + 64*64;  // [64][128]

  // ---- Layer 1: 67 -> 64 ----
  {
    float acc[4][8];
#pragma unroll
    for (int i=0;i<4;++i)
#pragma unroll
      for (int j=0;j<8;++j) acc[i][j]=0.f;
    for (int c = 0; c < 67; ++c) {
      float a0 = in_[(4*g+0)*67 + c];
      float a1 = in_[(4*g+1)*67 + c];
      float a2 = in_[(4*g+2)*67 + c];
      float a3 = in_[(4*g+3)*67 + c];
      const float* wr = w1T + c*64 + 8*h;
      float4 wv0 = *(const float4*)(wr);
      float4 wv1 = *(const float4*)(wr + 4);
      float wj[8] = {wv0.x,wv0.y,wv0.z,wv0.w,wv1.x,wv1.y,wv1.z,wv1.w};
#pragma unroll
      for (int j=0;j<8;++j) {
        acc[0][j] = fmaf(a0, wj[j], acc[0][j]);
        acc[1][j] = fmaf(a1, wj[j], acc[1][j]);
        acc[2][j] = fmaf(a2, wj[j], acc[2][j]);
        acc[3][j] = fmaf(a3, wj[j], acc[3][j]);
      }
    }
    float scl[8], shf[8];
#pragma unroll
    for (int j=0;j<8;++j) {
      int o = 8*h + j;
      float r = g1[o] * rsqrtf(v1[o] + 1e-5f);
      scl[j] = r;
      shf[j] = (b1[o] - m1[o]) * r + bt1[o];
    }
#pragma unroll
    for (int i=0;i<4;++i) {
      int k = 4*g + i;
#pragma unroll
      for (int j=0;j<8;++j)
        y_[k*65 + 8*h + j] = fmaxf(fmaf(acc[i][j], scl[j], shf[j]), 0.f);
    }
  }
  __syncthreads();

  // ---- Layer 2: 64 -> 64 (reads y_, writes in_ reused at stride 65) ----
  {
    float acc[4][8];
#pragma unroll
    for (int i=0;i<4;++i)
#pragma unroll
      for (int j=0;j<8;++j) acc[i][j]=0.f;
    for (int c = 0; c < 64; ++c) {
      float a0 = y_[(4*g+0)*65 + c];
      float a1 = y_[(4*g+1)*65 + c];
      float a2 = y_[(4*g+2)*65 + c];
      float a3 = y_[(4*g+3)*65 + c];
      const float* wr = w2T + c*64 + 8*h;
      float4 wv0 = *(const float4*)(wr);
      float4 wv1 = *(const float4*)(wr + 4);
      float wj[8] = {wv0.x,wv0.y,wv0.z,wv0.w,wv1.x,wv1.y,wv1.z,wv1.w};
#pragma unroll
      for (int j=0;j<8;++j) {
        acc[0][j] = fmaf(a0, wj[j], acc[0][j]);
        acc[1][j] = fmaf(a1, wj[j], acc[1][j]);
        acc[2][j] = fmaf(a2, wj[j], acc[2][j]);
        acc[3][j] = fmaf(a3, wj[j], acc[3][j]);
      }
    }
    float scl[8], shf[8];
#pragma unroll
    for (int j=0;j<8;++j) {
      int o = 8*h + j;
      float r = g2[o] * rsqrtf(v2[o] + 1e-5f);
      scl[j] = r;
      shf[j] = (b2[o] - m2[o]) * r + bt2[o];
    }
    __syncthreads();  // order old in_ reads before overwrite
#pragma unroll
    for (int i=0;i<4;++i) {
      int k = 4*g + i;
#pragma unroll
      for (int j=0;j<8;++j)
        in_[k*65 + 8*h + j] = fmaxf(fmaf(acc[i][j], scl[j], shf[j]), 0.f);
    }
  }
  __syncthreads();

  // ---- Layer 3: 64 -> 128 in two o-passes, BN+ReLU, maxpool over k, store ----
  for (int p = 0; p < 2; ++p) {
    float acc[4][8];
#pragma unroll
    for (int i=0;i<4;++i)
#pragma unroll
      for (int j=0;j<8;++j) acc[i][j]=0.f;
    for (int c = 0; c < 64; ++c) {
      float a0 = in_[(4*g+0)*65 + c];
      float a1 = in_[(4*g+1)*65 + c];
      float a2 = in_[(4*g+2)*65 + c];
      float a3 = in_[(4*g+3)*65 + c];
      const float* wr = w3T + c*128 + p*64 + 8*h;
      float4 wv0 = *(const float4*)(wr);
      float4 wv1 = *(const float4*)(wr + 4);
      float wj[8] = {wv0.x,wv0.y,wv0.z,wv0.w,wv1.x,wv1.y,wv1.z,wv1.w};
#pragma unroll
      for (int j=0;j<8;++j) {
        acc[0][j] = fmaf(a0, wj[j], acc[0][j]);
        acc[1][j] = fmaf(a1, wj[j], acc[1][j]);
        acc[2][j] = fmaf(a2, wj[j], acc[2][j]);
        acc[3][j] = fmaf(a3, wj[j], acc[3][j]);
      }
    }
    float scl[8], shf[8];
#pragma unroll
    for (int j=0;j<8;++j) {
      int o = p*64 + 8*h + j;
      float r = g3[o] * rsqrtf(v3[o] + 1e-5f);
      scl[j] = r;
      shf[j] = (b3[o] - m3[o]) * r + bt3[o];
    }
    float vm[8];
#pragma unroll
    for (int j=0;j<8;++j) {
      float q0 = fmaxf(fmaf(acc[0][j], scl[j], shf[j]), 0.f);
      float q1 = fmaxf(fmaf(acc[1][j], scl[j], shf[j]), 0.f);
      float q2 = fmaxf(fmaf(acc[2][j], scl[j], shf[j]), 0.f);
      float q3 = fmaxf(fmaf(acc[3][j], scl[j], shf[j]), 0.f);
      vm[j] = fmaxf(fmaxf(q0,q1), fmaxf(q2,q3));
    }
#pragma unroll
    for (int mk = 8; mk < 64; mk <<= 1) {
#pragma unroll
      for (int j=0;j<8;++j) vm[j] = fmaxf(vm[j], __shfl_xor(vm[j], mk));
    }
    if (g == 0) {
      float* dst = out_feats + (size_t)bid*128 + p*64 + 8*h;
      *(float4*)dst       = make_float4(vm[0],vm[1],vm[2],vm[3]);
      *(float4*)(dst + 4) = make_float4(vm[4],vm[5],vm[6],vm[7]);
    }
  }
}

// ---------------------------------------------------------------------------
extern "C" void kernel_launch(void* const* d_in, const int* in_sizes, int n_in,
                              void* d_out, int out_size, void* d_ws, size_t ws_size,
                              hipStream_t stream) {
  const float* xyzs  = (const float*)d_in[0];
  const float* feats = (const float*)d_in[1];
  const float* w1  = (const float*)d_in[2];
  const float* b1  = (const float*)d_in[3];
  const float* g1  = (const float*)d_in[4];
  const float* bt1 = (const float*)d_in[5];
  const float* m1  = (const float*)d_in[6];
  const float* v1  = (const float*)d_in[7];
  const float* w2  = (const float*)d_in[8];
  const float* b2  = (const float*)d_in[9];
  const float* g2  = (const float*)d_in[10];
  const float* bt2 = (const float*)d_in[11];
  const float* m2  = (const float*)d_in[12];
  const float* v2  = (const float*)d_in[13];
  const float* w3  = (const float*)d_in[14];
  const float* b3  = (const float*)d_in[15];
  const float* g3  = (const float*)d_in[16];
  const float* bt3 = (const float*)d_in[17];
  const float* m3  = (const float*)d_in[18];
  const float* v3  = (const float*)d_in[19];

  float* out       = (float*)d_out;
  float* centers   = out;                          // [8][2048][3]
  float* out_feats = out + (size_t)NB * SCTR * 3;  // [8][2048][128]
  float* wT        = (float*)d_ws;                 // 16576 floats

  // blocks 0..7: FPS; blocks 8..24: weight transpose (17 blocks x 1024 thr)
  hipLaunchKernelGGL(fps_transpose_kernel, dim3(NB + 17), dim3(1024), 0, stream,
                     xyzs, w1, w2, w3, centers, wT);
  hipLaunchKernelGGL(sa_fused_kernel, dim3(NB * SCTR), dim3(64), 0, stream,
                     xyzs, feats, centers, wT,
                     b1, g1, bt1, m1, v1,
                     b2, g2, bt2, m2, v2,
                     b3, g3, bt3, m3, v3,
                     out_feats);
}

// Round 10
// 2446.739 us; speedup vs baseline: 1.1239x; 1.1239x over previous
//
#include <hip/hip_runtime.h>

// PointNet++ SetAbstraction: FPS -> ball query -> grouped MLP(67->64->64->128, BN+ReLU) -> maxpool
// B=8, N=8192, S=2048, K=32, F=64.
//
// d_out: [8][2048][3] center_xyzs then [8][2048][128] center_feats (fp32).
// d_ws: 16576 floats of transposed weights.
//
// EXACTNESS INVARIANTS (validated R4..R9: absmax 7.8e-3 < 5.4e-2):
//   - discrete-decision math in contract(off) helpers; __f*_rn does NOT block FMA.
//   - np.sum last-axis n=3: FORWARD plain adds (x0+x1)+x2  [FPS dist, |c|^2, |x|^2]
//   - einsum dot: ascending FMA chain fma(c2,x2, fma(c1,x1, c0*x0))  [ball query]
//   - FPS argmax: u64 key (float_bits(bv)<<13)|(8191-idx); bv>=0 so float bits
//     monotone; pure max(key) == (max bv, tie -> min idx). Total order.
//   - packed v2f +,*: v_pk ops round identically to scalar per half (R9-validated).
//   - dual argmax chains: chain1's indices all > chain0's; merge with strict >
//     keeps first-index semantics.
//
// PERF LESSONS:
//   R5: dynamically-indexed per-thread arrays get LDS-demoted — named vectors only.
//   R6/R7: __shfl_* lowers to ds_permute (LDS pipe) — use DPP for reductions.
//   R8: DPP reduce -> 1998 us @ 512 thr; ~85% VALUBusy on active CUs.
//   R9: 1024 thr REGRESSED (2220 us): barrier skew + reduce issue scale with
//       wave count; no hideable latency left. 512 thr is the sweet spot.
//   R10: R8 config + packed v2f dist + dual independent argmax chains.
//   sa_fused_kernel byte-identical to R4 (527 us steady; VALU-issue-bound,
//   ~84% of its cycles are the MLP fmas -> fp32 floor ~440 us).

#define NPTS 8192
#define SCTR 2048
#define NB   8
#define KNN  32
#define NF   64

typedef float v2f __attribute__((ext_vector_type(2)));

// d = (dx*dx + dy*dy) + dz*dz for TWO points, exact fp32 mul/add order,
// NO contraction (v_pk_add_f32 / v_pk_mul_f32 — same IEEE rounding as scalar).
__device__ __forceinline__ v2f fps_sqdist_v2(v2f px, v2f py, v2f pz,
                                             v2f lx, v2f ly, v2f lz) {
#pragma clang fp contract(off)
  v2f dx = px - lx;
  v2f dy = py - ly;
  v2f dz = pz - lz;
  v2f xx = dx * dx;
  v2f yy = dy * dy;
  v2f zz = dz * dz;
  return (xx + yy) + zz;
}

// (x*x + y*y) + z*z, NO contraction (np.sum forward order, n=3).
__device__ __forceinline__ float sumsq3(float x, float y, float z) {
#pragma clang fp contract(off)
  return (x * x + y * y) + z * z;
}

// Ball-query expanded form: (sc + sx) - 2*dot, NO contraction on the adds.
// dot = ascending-k FMA chain: fma(cz,z, fma(cy,y, cx*x)).
__device__ __forceinline__ float bq_d2(float sc, float sx,
                                       float cx, float cy, float cz,
                                       float x, float y, float z) {
#pragma clang fp contract(off)
  float dt = fmaf(cz, z, fmaf(cy, y, cx * x));
  return (sc + sx) - 2.0f * dt;
}

// u64 max with the partner lane's key fetched via DPP (VALU pipe, no LDS).
// old=src (self): bound-disabled lanes combine with themselves (idempotent max).
template <int CTRL>
__device__ __forceinline__ unsigned long long kmax_dpp(unsigned long long k) {
  int lo = (int)(unsigned int)(k & 0xFFFFFFFFull);
  int hi = (int)(unsigned int)(k >> 32);
  int slo = __builtin_amdgcn_update_dpp(lo, lo, CTRL, 0xF, 0xF, false);
  int shi = __builtin_amdgcn_update_dpp(hi, hi, CTRL, 0xF, 0xF, false);
  unsigned long long sk =
      ((unsigned long long)(unsigned int)shi << 32) | (unsigned int)slo;
  return sk > k ? sk : k;
}

// ---------------------------------------------------------------------------
// Kernel 1: blocks 0..7 = FPS (one block per batch, 512 thr = 8 waves,
// 16 points/thread in NAMED float4 registers, packed-f32 distances, dual
// argmax chains); blocks 8..40 = weight transpose. DPP reductions; LDS only
// for 8 wave-best slots, winner-coord broadcast, and writeback.
// ---------------------------------------------------------------------------
__global__ __launch_bounds__(512, 2) void fps_transpose_kernel(
    const float* __restrict__ xyzs,
    const float* __restrict__ w1, const float* __restrict__ w2, const float* __restrict__ w3,
    float* __restrict__ centers, float* __restrict__ wT)
{
  const int t = threadIdx.x;
  if (blockIdx.x >= NB) {
    int idx = (blockIdx.x - NB) * 512 + t;
    if (idx < 67*64) {
      int c = idx >> 6, o = idx & 63;
      wT[idx] = w1[o*67 + c];
    } else if (idx < 67*64 + 64*64) {
      int r = idx - 67*64; int c = r >> 6, o = r & 63;
      wT[idx] = w2[o*64 + c];
    } else if (idx < 67*64 + 64*64 + 64*128) {
      int r = idx - (67*64 + 64*64); int c = r >> 7, o = r & 127;
      wT[idx] = w3[o*64 + c];
    }
    return;
  }

  const int b = blockIdx.x;
  const float* xb = xyzs + (size_t)b * NPTS * 3;

  __shared__ float sX[NPTS], sY[NPTS], sZ[NPTS];         // 96 KB planar coords
  __shared__ unsigned long long redk[2][8];              // wave-best keys
  __shared__ int hist[SCTR];                             // 8 KB

  // One-time fill of the planar LDS copies (off the hot path).
  for (int i = t; i < NPTS; i += 512) {
    sX[i] = xb[3*i+0];
    sY[i] = xb[3*i+1];
    sZ[i] = xb[3*i+2];
  }
  if (t == 0) hist[0] = 0;   // reference: first center is index 0
  __syncthreads();

  const int t4 = 4 * t;

  // 16 loop-invariant points (4 quads strided 2048) in NAMED registers.
  const float4 xA = *(const float4*)(sX + 0    + t4);
  const float4 yA = *(const float4*)(sY + 0    + t4);
  const float4 zA = *(const float4*)(sZ + 0    + t4);
  const float4 xB = *(const float4*)(sX + 2048 + t4);
  const float4 yB = *(const float4*)(sY + 2048 + t4);
  const float4 zB = *(const float4*)(sZ + 2048 + t4);
  const float4 xC = *(const float4*)(sX + 4096 + t4);
  const float4 yC = *(const float4*)(sY + 4096 + t4);
  const float4 zC = *(const float4*)(sZ + 4096 + t4);
  const float4 xD = *(const float4*)(sX + 6144 + t4);
  const float4 yD = *(const float4*)(sY + 6144 + t4);
  const float4 zD = *(const float4*)(sZ + 6144 + t4);

  float4 mA = make_float4(1e10f,1e10f,1e10f,1e10f);
  float4 mB = mA, mC = mA, mD = mA;

  float lx = sX[0], ly = sY[0], lz = sZ[0];

  for (int s = 1; s < SCTR; ++s) {
    // Two independent argmax chains (halved dependency depth). Chain 0 covers
    // indices {t4.., 2048+t4..}, chain 1 covers {4096+t4.., 6144+t4..} — every
    // chain-1 index exceeds every chain-0 index.
    float bv0 = -1.0f, bv1 = -1.0f; int bg0 = 0, bg1 = 0;
    {
      v2f lxv = {lx, lx}, lyv = {ly, ly}, lzv = {lz, lz};
      v2f d;

      d = fps_sqdist_v2((v2f){xA.x,xA.y}, (v2f){yA.x,yA.y}, (v2f){zA.x,zA.y},
                        lxv, lyv, lzv);
      mA.x = fminf(mA.x, d.x); if (mA.x > bv0) { bv0 = mA.x; bg0 = t4 + 0; }
      mA.y = fminf(mA.y, d.y); if (mA.y > bv0) { bv0 = mA.y; bg0 = t4 + 1; }
      d = fps_sqdist_v2((v2f){xA.z,xA.w}, (v2f){yA.z,yA.w}, (v2f){zA.z,zA.w},
                        lxv, lyv, lzv);
      mA.z = fminf(mA.z, d.x); if (mA.z > bv0) { bv0 = mA.z; bg0 = t4 + 2; }
      mA.w = fminf(mA.w, d.y); if (mA.w > bv0) { bv0 = mA.w; bg0 = t4 + 3; }

      d = fps_sqdist_v2((v2f){xB.x,xB.y}, (v2f){yB.x,yB.y}, (v2f){zB.x,zB.y},
                        lxv, lyv, lzv);
      mB.x = fminf(mB.x, d.x); if (mB.x > bv0) { bv0 = mB.x; bg0 = 2048 + t4 + 0; }
      mB.y = fminf(mB.y, d.y); if (mB.y > bv0) { bv0 = mB.y; bg0 = 2048 + t4 + 1; }
      d = fps_sqdist_v2((v2f){xB.z,xB.w}, (v2f){yB.z,yB.w}, (v2f){zB.z,zB.w},
                        lxv, lyv, lzv);
      mB.z = fminf(mB.z, d.x); if (mB.z > bv0) { bv0 = mB.z; bg0 = 2048 + t4 + 2; }
      mB.w = fminf(mB.w, d.y); if (mB.w > bv0) { bv0 = mB.w; bg0 = 2048 + t4 + 3; }

      d = fps_sqdist_v2((v2f){xC.x,xC.y}, (v2f){yC.x,yC.y}, (v2f){zC.x,zC.y},
                        lxv, lyv, lzv);
      mC.x = fminf(mC.x, d.x); if (mC.x > bv1) { bv1 = mC.x; bg1 = 4096 + t4 + 0; }
      mC.y = fminf(mC.y, d.y); if (mC.y > bv1) { bv1 = mC.y; bg1 = 4096 + t4 + 1; }
      d = fps_sqdist_v2((v2f){xC.z,xC.w}, (v2f){yC.z,yC.w}, (v2f){zC.z,zC.w},
                        lxv, lyv, lzv);
      mC.z = fminf(mC.z, d.x); if (mC.z > bv1) { bv1 = mC.z; bg1 = 4096 + t4 + 2; }
      mC.w = fminf(mC.w, d.y); if (mC.w > bv1) { bv1 = mC.w; bg1 = 4096 + t4 + 3; }

      d = fps_sqdist_v2((v2f){xD.x,xD.y}, (v2f){yD.x,yD.y}, (v2f){zD.x,zD.y},
                        lxv, lyv, lzv);
      mD.x = fminf(mD.x, d.x); if (mD.x > bv1) { bv1 = mD.x; bg1 = 6144 + t4 + 0; }
      mD.y = fminf(mD.y, d.y); if (mD.y > bv1) { bv1 = mD.y; bg1 = 6144 + t4 + 1; }
      d = fps_sqdist_v2((v2f){xD.z,xD.w}, (v2f){yD.z,yD.w}, (v2f){zD.z,zD.w},
                        lxv, lyv, lzv);
      mD.z = fminf(mD.z, d.x); if (mD.z > bv1) { bv1 = mD.z; bg1 = 6144 + t4 + 2; }
      mD.w = fminf(mD.w, d.y); if (mD.w > bv1) { bv1 = mD.w; bg1 = 6144 + t4 + 3; }
    }
    // Merge: strict > keeps chain 0 on ties (its indices are all smaller).
    float bv = bv0; int bg = bg0;
    if (bv1 > bv0) { bv = bv1; bg = bg1; }

    // Pack: bv >= 0, so float bits are order-monotone.
    unsigned long long key =
        ((unsigned long long)__float_as_uint(bv) << 13) |
        (unsigned long long)(8191 - bg);

    // Wave-level max on the VALU pipe; lane 63 holds the wave max after this.
    key = kmax_dpp<0x111>(key);   // row_shr:1
    key = kmax_dpp<0x112>(key);   // row_shr:2
    key = kmax_dpp<0x114>(key);   // row_shr:4
    key = kmax_dpp<0x118>(key);   // row_shr:8
    key = kmax_dpp<0x142>(key);   // row_bcast:15
    key = kmax_dpp<0x143>(key);   // row_bcast:31

    int pb = s & 1;   // double-buffered slots: one barrier per step
    if ((t & 63) == 63) redk[pb][t >> 6] = key;
    __syncthreads();

    // Cross-wave: lane reads slot (lane&7), then 3-hop mini-max over the
    // replicated 8-entry groups (quad_perm xor1, xor2, row_ror:4).
    unsigned long long k8 = redk[pb][t & 7];
    k8 = kmax_dpp<0xB1>(k8);      // quad_perm [1,0,3,2]
    k8 = kmax_dpp<0x4E>(k8);      // quad_perm [2,3,0,1]
    k8 = kmax_dpp<0x124>(k8);     // row_ror:4

    int i0 = 8191 - (int)(k8 & 0x1FFFull);
    // Winner coords: broadcast LDS reads (same address all lanes — free).
    lx = sX[i0]; ly = sY[i0]; lz = sZ[i0];
    if (t == 0) hist[s] = i0;
  }
  __syncthreads();

  for (int s = t; s < SCTR; s += 512) {
    int i = hist[s];
    float* o = centers + ((size_t)b * SCTR + s) * 3;
    o[0] = sX[i]; o[1] = sY[i]; o[2] = sZ[i];
  }
}

// ---------------------------------------------------------------------------
// Kernel 2: one 64-thread wave per center. Ball query (first K ascending
// index within radius, exact expanded-form d2), gather to LDS, 3-layer MLP
// with per-lane 4k x 8o register tile, BN+ReLU, maxpool over K, store.
// (byte-identical to the R4 passing version)
// ---------------------------------------------------------------------------
__global__ __launch_bounds__(64) void sa_fused_kernel(
    const float* __restrict__ xyzs, const float* __restrict__ feats,
    const float* centers, const float* __restrict__ wT,
    const float* __restrict__ b1, const float* __restrict__ g1, const float* __restrict__ bt1,
    const float* __restrict__ m1, const float* __restrict__ v1,
    const float* __restrict__ b2, const float* __restrict__ g2, const float* __restrict__ bt2,
    const float* __restrict__ m2, const float* __restrict__ v2,
    const float* __restrict__ b3, const float* __restrict__ g3, const float* __restrict__ bt3,
    const float* __restrict__ m3, const float* __restrict__ v3,
    float* out_feats)
{
  constexpr float R2 = (float)(0.2 * 0.2);  // f32(0.04000000000000001) — matches ref predicate
  const int bid  = blockIdx.x;
  const int b    = bid >> 11;
  const int lane = threadIdx.x;
  const float* xb = xyzs + (size_t)b * NPTS * 3;
  const float* cp = centers + (size_t)bid * 3;
  float cx = cp[0], cy = cp[1], cz = cp[2];
  float sc = sumsq3(cx, cy, cz);

  __shared__ int   gidx[KNN];
  __shared__ float in_[32*67];   // stride 67 (conflict-free for the 4k in-reads)
  __shared__ float y_[32*65];    // stride 65

  // ---- ball query: first 32 in-radius points by ascending index ----
  int cnt = 0;
  for (int base = 0; base < NPTS && cnt < KNN; base += 64) {
    int n = base + lane;
    float x = xb[n*3+0], y = xb[n*3+1], z = xb[n*3+2];
    float sx = sumsq3(x, y, z);
    float d2 = bq_d2(sc, sx, cx, cy, cz, x, y, z);
    bool within = (d2 <= R2);
    unsigned long long mk = __ballot(within);
    int rank = __popcll(mk & ((1ull << lane) - 1ull));
    int slot = cnt + rank;
    if (within && slot < KNN) gidx[slot] = n;
    cnt += (int)__popcll(mk);
  }
  if (cnt > KNN) cnt = KNN;
  __syncthreads();

  // ---- gather: in_[k][0..2] = xyz - center, in_[k][3..66] = feats; zeros if invalid ----
#pragma unroll 4
  for (int k = 0; k < KNN; ++k) {
    int gk = (k < cnt) ? gidx[k] : -1;
    float fv = 0.f, xv = 0.f;
    if (gk >= 0) {
      fv = feats[((size_t)b * NPTS + gk) * NF + lane];
      if (lane < 3) xv = xb[gk*3 + lane] - cp[lane];  // exact single op
    }
    in_[k*67 + 3 + lane] = fv;
    if (lane < 3) in_[k*67 + lane] = xv;
  }
  __syncthreads();

  const int g = lane >> 3;  // k-group: k = 4g..4g+3
  const int h = lane & 7;   // o-group: o = 8h..8h+7
  const float* w1T = wT;                  // [67][64]
  const float* w2T = wT + 67*64;          // [64][64]
  const float* w3T = wT + 67*64 + 64*64;  // [64][128]

  // ---- Layer 1: 67 -> 64 ----
  {
    float acc[4][8];
#pragma unroll
    for (int i=0;i<4;++i)
#pragma unroll
      for (int j=0;j<8;++j) acc[i][j]=0.f;
    for (int c = 0; c < 67; ++c) {
      float a0 = in_[(4*g+0)*67 + c];
      float a1 = in_[(4*g+1)*67 + c];
      float a2 = in_[(4*g+2)*67 + c];
      float a3 = in_[(4*g+3)*67 + c];
      const float* wr = w1T + c*64 + 8*h;
      float4 wv0 = *(const float4*)(wr);
      float4 wv1 = *(const float4*)(wr + 4);
      float wj[8] = {wv0.x,wv0.y,wv0.z,wv0.w,wv1.x,wv1.y,wv1.z,wv1.w};
#pragma unroll
      for (int j=0;j<8;++j) {
        acc[0][j] = fmaf(a0, wj[j], acc[0][j]);
        acc[1][j] = fmaf(a1, wj[j], acc[1][j]);
        acc[2][j] = fmaf(a2, wj[j], acc[2][j]);
        acc[3][j] = fmaf(a3, wj[j], acc[3][j]);
      }
    }
    float scl[8], shf[8];
#pragma unroll
    for (int j=0;j<8;++j) {
      int o = 8*h + j;
      float r = g1[o] * rsqrtf(v1[o] + 1e-5f);
      scl[j] = r;
      shf[j] = (b1[o] - m1[o]) * r + bt1[o];
    }
#pragma unroll
    for (int i=0;i<4;++i) {
      int k = 4*g + i;
#pragma unroll
      for (int j=0;j<8;++j)
        y_[k*65 + 8*h + j] = fmaxf(fmaf(acc[i][j], scl[j], shf[j]), 0.f);
    }
  }
  __syncthreads();

  // ---- Layer 2: 64 -> 64 (reads y_, writes in_ reused at stride 65) ----
  {
    float acc[4][8];
#pragma unroll
    for (int i=0;i<4;++i)
#pragma unroll
      for (int j=0;j<8;++j) acc[i][j]=0.f;
    for (int c = 0; c < 64; ++c) {
      float a0 = y_[(4*g+0)*65 + c];
      float a1 = y_[(4*g+1)*65 + c];
      float a2 = y_[(4*g+2)*65 + c];
      float a3 = y_[(4*g+3)*65 + c];
      const float* wr = w2T + c*64 + 8*h;
      float4 wv0 = *(const float4*)(wr);
      float4 wv1 = *(const float4*)(wr + 4);
      float wj[8] = {wv0.x,wv0.y,wv0.z,wv0.w,wv1.x,wv1.y,wv1.z,wv1.w};
#pragma unroll
      for (int j=0;j<8;++j) {
        acc[0][j] = fmaf(a0, wj[j], acc[0][j]);
        acc[1][j] = fmaf(a1, wj[j], acc[1][j]);
        acc[2][j] = fmaf(a2, wj[j], acc[2][j]);
        acc[3][j] = fmaf(a3, wj[j], acc[3][j]);
      }
    }
    float scl[8], shf[8];
#pragma unroll
    for (int j=0;j<8;++j) {
      int o = 8*h + j;
      float r = g2[o] * rsqrtf(v2[o] + 1e-5f);
      scl[j] = r;
      shf[j] = (b2[o] - m2[o]) * r + bt2[o];
    }
    __syncthreads();  // order old in_ reads before overwrite
#pragma unroll
    for (int i=0;i<4;++i) {
      int k = 4*g + i;
#pragma unroll
      for (int j=0;j<8;++j)
        in_[k*65 + 8*h + j] = fmaxf(fmaf(acc[i][j], scl[j], shf[j]), 0.f);
    }
  }
  __syncthreads();

  // ---- Layer 3: 64 -> 128 in two o-passes, BN+ReLU, maxpool over k, store ----
  for (int p = 0; p < 2; ++p) {
    float acc[4][8];
#pragma unroll
    for (int i=0;i<4;++i)
#pragma unroll
      for (int j=0;j<8;++j) acc[i][j]=0.f;
    for (int c = 0; c < 64; ++c) {
      float a0 = in_[(4*g+0)*65 + c];
      float a1 = in_[(4*g+1)*65 + c];
      float a2 = in_[(4*g+2)*65 + c];
      float a3 = in_[(4*g+3)*65 + c];
      const float* wr = w3T + c*128 + p*64 + 8*h;
      float4 wv0 = *(const float4*)(wr);
      float4 wv1 = *(const float4*)(wr + 4);
      float wj[8] = {wv0.x,wv0.y,wv0.z,wv0.w,wv1.x,wv1.y,wv1.z,wv1.w};
#pragma unroll
      for (int j=0;j<8;++j) {
        acc[0][j] = fmaf(a0, wj[j], acc[0][j]);
        acc[1][j] = fmaf(a1, wj[j], acc[1][j]);
        acc[2][j] = fmaf(a2, wj[j], acc[2][j]);
        acc[3][j] = fmaf(a3, wj[j], acc[3][j]);
      }
    }
    float scl[8], shf[8];
#pragma unroll
    for (int j=0;j<8;++j) {
      int o = p*64 + 8*h + j;
      float r = g3[o] * rsqrtf(v3[o] + 1e-5f);
      scl[j] = r;
      shf[j] = (b3[o] - m3[o]) * r + bt3[o];
    }
    float vm[8];
#pragma unroll
    for (int j=0;j<8;++j) {
      float q0 = fmaxf(fmaf(acc[0][j], scl[j], shf[j]), 0.f);
      float q1 = fmaxf(fmaf(acc[1][j], scl[j], shf[j]), 0.f);
      float q2 = fmaxf(fmaf(acc[2][j], scl[j], shf[j]), 0.f);
      float q3 = fmaxf(fmaf(acc[3][j], scl[j], shf[j]), 0.f);
      vm[j] = fmaxf(fmaxf(q0,q1), fmaxf(q2,q3));
    }
#pragma unroll
    for (int mk = 8; mk < 64; mk <<= 1) {
#pragma unroll
      for (int j=0;j<8;++j) vm[j] = fmaxf(vm[j], __shfl_xor(vm[j], mk));
    }
    if (g == 0) {
      float* dst = out_feats + (size_t)bid*128 + p*64 + 8*h;
      *(float4*)dst       = make_float4(vm[0],vm[1],vm[2],vm[3]);
      *(float4*)(dst + 4) = make_float4(vm[4],vm[5],vm[6],vm[7]);
    }
  }
}

// ---------------------------------------------------------------------------
extern "C" void kernel_launch(void* const* d_in, const int* in_sizes, int n_in,
                              void* d_out, int out_size, void* d_ws, size_t ws_size,
                              hipStream_t stream) {
  const float* xyzs  = (const float*)d_in[0];
  const float* feats = (const float*)d_in[1];
  const float* w1  = (const float*)d_in[2];
  const float* b1  = (const float*)d_in[3];
  const float* g1  = (const float*)d_in[4];
  const float* bt1 = (const float*)d_in[5];
  const float* m1  = (const float*)d_in[6];
  const float* v1  = (const float*)d_in[7];
  const float* w2  = (const float*)d_in[8];
  const float* b2  = (const float*)d_in[9];
  const float* g2  = (const float*)d_in[10];
  const float* bt2 = (const float*)d_in[11];
  const float* m2  = (const float*)d_in[12];
  const float* v2  = (const float*)d_in[13];
  const float* w3  = (const float*)d_in[14];
  const float* b3  = (const float*)d_in[15];
  const float* g3  = (const float*)d_in[16];
  const float* bt3 = (const float*)d_in[17];
  const float* m3  = (const float*)d_in[18];
  const float* v3  = (const float*)d_in[19];

  float* out       = (float*)d_out;
  float* centers   = out;                          // [8][2048][3]
  float* out_feats = out + (size_t)NB * SCTR * 3;  // [8][2048][128]
  float* wT        = (float*)d_ws;                 // 16576 floats

  // blocks 0..7: FPS; blocks 8..40: weight transpose (33 blocks x 512 thr)
  hipLaunchKernelGGL(fps_transpose_kernel, dim3(NB + 33), dim3(512), 0, stream,
                     xyzs, w1, w2, w3, centers, wT);
  hipLaunchKernelGGL(sa_fused_kernel, dim3(NB * SCTR), dim3(64), 0, stream,
                     xyzs, feats, centers, wT,
                     b1, g1, bt1, m1, v1,
                     b2, g2, bt2, m2, v2,
                     b3, g3, bt3, m3, v3,
                     out_feats);
}